// Round 4
// baseline (6477.409 us; speedup 1.0000x reference)
//
#include <hip/hip_runtime.h>
#include <math.h>

#define T_STEPS 512
#define NF 4
#define HID 32
#define BN_EPS 1e-5f

typedef float f32x2 __attribute__((ext_vector_type(2)));
typedef float f32x4 __attribute__((ext_vector_type(4)));

__device__ __forceinline__ f32x2 fma2(f32x2 a, f32x2 b, f32x2 c) {
  return __builtin_elementwise_fma(a, b, c);
}
__device__ __forceinline__ float fsigmoid(float x) {
  return __builtin_amdgcn_rcpf(1.0f + __expf(-x));   // validated r1/r3: absmax 2e-3
}
__device__ __forceinline__ float ftanh(float x) {
  return fmaf(__builtin_amdgcn_rcpf(1.0f + __expf(-2.0f * x)), 2.0f, -1.0f);
}
template <int CTRL>
__device__ __forceinline__ float dpp_add(float v) {
  int s = __builtin_amdgcn_update_dpp(0, __builtin_bit_cast(int, v), CTRL, 0xf, 0xf, true);
  return v + __builtin_bit_cast(float, s);
}

// Wave = 2 batch rows (A = lower-half's row duties, B = upper-half's).
// Lane layout: u = lane&31, half = (lane>>5)&1.
//   lower lane u owns gate-rows i_u, f_u; upper owns g_u, o_u — each computed
//   for BOTH rows A and B. This halves per-lane weight registers (128->64)
//   vs round 3, targeting real 4-waves/SIMD residency (round 3: 2, AGPR split).
__global__ __launch_bounds__(256, 4) void hedge_kernel(
    const float* __restrict__ x,
    const float* __restrict__ bn_g, const float* __restrict__ bn_b,
    const float* __restrict__ bn_m, const float* __restrict__ bn_v,
    const float* __restrict__ W_ih, const float* __restrict__ b_ih,
    const float* __restrict__ W_hh, const float* __restrict__ b_hh,
    const float* __restrict__ W1,   const float* __restrict__ b1,
    const float* __restrict__ W2,   const float* __restrict__ b2,
    float* __restrict__ out)
{
  __shared__ __align__(16) float sh[4][2][HID];   // [wave][row][unit], 1 KB

  const int tid  = threadIdx.x;
  const int u    = tid & 31;
  const int half = (tid >> 5) & 1;
  const int wv   = __builtin_amdgcn_readfirstlane(tid >> 6);  // scalar wave id
  const int rowA = (blockIdx.x * 4 + wv) * 2;

  // ---- fold BatchNorm (z*scale + shift) into W_ih' and bias
  float scale[5], shift[5];
  #pragma unroll
  for (int f = 0; f < 5; ++f) {
    float s = bn_g[f] * rsqrtf(bn_v[f] + BN_EPS);
    scale[f] = s;
    shift[f] = fmaf(-bn_m[f], s, bn_b[f]);
  }

  // gate rows owned by this lane: r0 = i_u (lower) / g_u (upper), r1 = f_u / o_u
  const int r0 = half * 64 + u;
  const int r1 = r0 + 32;

  f32x2 wh0[16], wh1[16];     // W_hh rows r0, r1 (64 regs total)
  f32x2 wx0a, wx0b, wx1a, wx1b;
  float wd0, wd1, bias0, bias1;
  {
    float ws[5], acc = b_ih[r0] + b_hh[r0];
    #pragma unroll
    for (int f = 0; f < 5; ++f) {
      float w = W_ih[r0 * 5 + f];
      ws[f] = w * scale[f];
      acc = fmaf(w, shift[f], acc);
    }
    wx0a = (f32x2){ws[0], ws[1]}; wx0b = (f32x2){ws[2], ws[3]};
    wd0 = ws[4]; bias0 = acc;
    #pragma unroll
    for (int p = 0; p < 16; ++p) wh0[p] = *(const f32x2*)&W_hh[r0 * HID + 2 * p];
  }
  {
    float ws[5], acc = b_ih[r1] + b_hh[r1];
    #pragma unroll
    for (int f = 0; f < 5; ++f) {
      float w = W_ih[r1 * 5 + f];
      ws[f] = w * scale[f];
      acc = fmaf(w, shift[f], acc);
    }
    wx1a = (f32x2){ws[0], ws[1]}; wx1b = (f32x2){ws[2], ws[3]};
    wd1 = ws[4]; bias1 = acc;
    #pragma unroll
    for (int p = 0; p < 16; ++p) wh1[p] = *(const f32x2*)&W_hh[r1 * HID + 2 * p];
  }

  // MLP: lane handles unit u, k-half [half*16, half*16+16), both rows (16 regs)
  f32x2 w1h[8];
  #pragma unroll
  for (int p = 0; p < 8; ++p)
    w1h[p] = *(const f32x2*)&W1[u * HID + half * 16 + 2 * p];
  const float b1u = b1[u];
  const float w2u = W2[u];
  const float b2s = b2[0];

  const float* xA = x + (size_t)rowA * (T_STEPS * NF);
  const float* xB = xA + T_STEPS * NF;
  float* orow = out + ((size_t)rowA + half) * T_STEPS;

  float c = 0.0f, h = 0.0f;

  // acc[gate-row][batch-row], f32x2 pk partials; init = bias + x_0 terms
  f32x2 acc00, acc01, acc10, acc11;
  {
    const f32x4 x0A = *(const f32x4*)xA;
    const f32x4 x0B = *(const f32x4*)xB;
    const f32x2 a01 = (f32x2){x0A.x, x0A.y}, a23 = (f32x2){x0A.z, x0A.w};
    const f32x2 b01 = (f32x2){x0B.x, x0B.y}, b23 = (f32x2){x0B.z, x0B.w};
    acc00 = fma2(wx0a, a01, fma2(wx0b, a23, (f32x2){bias0, 0.f}));
    acc01 = fma2(wx0a, b01, fma2(wx0b, b23, (f32x2){bias0, 0.f}));
    acc10 = fma2(wx1a, a01, fma2(wx1b, a23, (f32x2){bias1, 0.f}));
    acc11 = fma2(wx1a, b01, fma2(wx1b, b23, (f32x2){bias1, 0.f}));
  }

  const f32x4* shA4 = (const f32x4*)&sh[wv][0][0];          // full-wave broadcast
  const f32x4* shB4 = (const f32x4*)&sh[wv][1][0];
  const f32x4* mA4  = (const f32x4*)&sh[wv][0][half * 16];  // 2-group broadcast (free)
  const f32x4* mB4  = (const f32x4*)&sh[wv][1][half * 16];

  #pragma unroll 1
  for (int t = 0; t < T_STEPS; ++t) {
    const int tn = (t + 1 < T_STEPS) ? t + 1 : t;
    const f32x4 xnA = *(const f32x4*)(xA + tn * NF);   // prefetch x_{t+1}
    const f32x4 xnB = *(const f32x4*)(xB + tn * NF);

    // ---- finalize step-t gate pre-activations
    const float gA0 = acc00.x + acc00.y;   // my r0 gate, row A
    const float gB0 = acc01.x + acc01.y;
    const float gA1 = acc10.x + acc10.y;
    const float gB1 = acc11.x + acc11.y;

    // exchange: lower keeps row A (needs g,o from upper); upper keeps row B (needs i,f)
    const float s0 = half ? gA0 : gB0;     // upper sends g^A, lower sends i^B
    const float s1 = half ? gA1 : gB1;     // upper sends o^A, lower sends f^B
    const float q0 = __shfl_xor(s0, 32);
    const float q1 = __shfl_xor(s1, 32);
    const float gi = half ? q0 : gA0;
    const float gf = half ? q1 : gA1;
    const float gg = half ? gB0 : q0;
    const float go = half ? gB1 : q1;

    const float I = fsigmoid(gi);
    const float F = fsigmoid(gf);
    const float G = ftanh(gg);
    const float O = fsigmoid(go);
    c = fmaf(F, c, I * G);
    h = O * ftanh(c);
    sh[wv][half][u] = h;     // lower -> row A slot, upper -> row B (same wave: lgkmcnt orders)

    // ---- acc(t+1) = bias + x_{t+1} contribution
    {
      const f32x2 a01 = (f32x2){xnA.x, xnA.y}, a23 = (f32x2){xnA.z, xnA.w};
      const f32x2 b01 = (f32x2){xnB.x, xnB.y}, b23 = (f32x2){xnB.z, xnB.w};
      acc00 = fma2(wx0a, a01, fma2(wx0b, a23, (f32x2){bias0, 0.f}));
      acc01 = fma2(wx0a, b01, fma2(wx0b, b23, (f32x2){bias0, 0.f}));
      acc10 = fma2(wx1a, a01, fma2(wx1b, a23, (f32x2){bias1, 0.f}));
      acc11 = fma2(wx1a, b01, fma2(wx1b, b23, (f32x2){bias1, 0.f}));
    }

    // ---- h_t -> gates(t+1): 64 pk_fma (independent of MLP below; compiler overlaps)
    #pragma unroll
    for (int i = 0; i < 8; ++i) {
      const f32x4 hA = shA4[i];
      const f32x4 hB = shB4[i];
      const f32x2 a01 = (f32x2){hA.x, hA.y}, a23 = (f32x2){hA.z, hA.w};
      const f32x2 b01 = (f32x2){hB.x, hB.y}, b23 = (f32x2){hB.z, hB.w};
      acc00 = fma2(wh0[2*i], a01, acc00); acc00 = fma2(wh0[2*i+1], a23, acc00);
      acc01 = fma2(wh0[2*i], b01, acc01); acc01 = fma2(wh0[2*i+1], b23, acc01);
      acc10 = fma2(wh1[2*i], a01, acc10); acc10 = fma2(wh1[2*i+1], a23, acc10);
      acc11 = fma2(wh1[2*i], b01, acc11); acc11 = fma2(wh1[2*i+1], b23, acc11);
    }

    // ---- decision MLP on h_t: unit u, my k-half, both rows
    f32x2 pa = (f32x2){0.f, 0.f}, pb = (f32x2){0.f, 0.f};
    #pragma unroll
    for (int i = 0; i < 4; ++i) {
      const f32x4 hA = mA4[i];
      const f32x4 hB = mB4[i];
      pa = fma2(w1h[2*i],   (f32x2){hA.x, hA.y}, pa);
      pa = fma2(w1h[2*i+1], (f32x2){hA.z, hA.w}, pa);
      pb = fma2(w1h[2*i],   (f32x2){hB.x, hB.y}, pb);
      pb = fma2(w1h[2*i+1], (f32x2){hB.z, hB.w}, pb);
    }
    const float pA = pa.x + pa.y;
    const float pB = pb.x + pb.y;
    const float ms = half ? pA : pB;         // send the partial the OTHER half completes
    const float mr = __shfl_xor(ms, 32);
    const float mval = (half ? pB : pA) + mr + b1u;  // lower: full m_A[u]; upper: full m_B[u]
    float rv = fmaxf(mval, 0.f) * w2u;
    rv = dpp_add<0x111>(rv);   // row_shr:1
    rv = dpp_add<0x112>(rv);   // row_shr:2
    rv = dpp_add<0x114>(rv);   // row_shr:4
    rv = dpp_add<0x118>(rv);   // row_shr:8 -> lanes 15/31/47/63 = row-of-16 sums
    rv = dpp_add<0x142>(rv);   // row_bcast:15 -> lane31 = sum(0..31), lane63 = sum(32..63)
    const float sv = fsigmoid(rv + b2s);
    const float dA = __builtin_bit_cast(float, __builtin_amdgcn_readlane(__builtin_bit_cast(int, sv), 31));
    const float dB = __builtin_bit_cast(float, __builtin_amdgcn_readlane(__builtin_bit_cast(int, sv), 63));

    // d_t term of gates(t+1)
    acc00.x = fmaf(wd0, dA, acc00.x);
    acc01.x = fmaf(wd0, dB, acc01.x);
    acc10.x = fmaf(wd1, dA, acc10.x);
    acc11.x = fmaf(wd1, dB, acc11.x);

    if (u == 0) orow[t] = half ? dB : dA;    // lane0 -> row A, lane32 -> row B
  }
}

extern "C" void kernel_launch(void* const* d_in, const int* in_sizes, int n_in,
                              void* d_out, int out_size, void* d_ws, size_t ws_size,
                              hipStream_t stream) {
  const float* x    = (const float*)d_in[0];
  const float* bn_g = (const float*)d_in[1];
  const float* bn_b = (const float*)d_in[2];
  const float* bn_m = (const float*)d_in[3];
  const float* bn_v = (const float*)d_in[4];
  const float* W_ih = (const float*)d_in[5];
  const float* b_ih = (const float*)d_in[6];
  const float* W_hh = (const float*)d_in[7];
  const float* b_hh = (const float*)d_in[8];
  const float* W1   = (const float*)d_in[9];
  const float* b1   = (const float*)d_in[10];
  const float* W2   = (const float*)d_in[11];
  const float* b2   = (const float*)d_in[12];
  float* out = (float*)d_out;

  const int B = in_sizes[0] / (T_STEPS * NF);   // 8192
  const int grid = B / 8;                       // 8 rows per 256-thread block -> 1024

  hipLaunchKernelGGL(hedge_kernel, dim3(grid), dim3(256), 0, stream,
                     x, bn_g, bn_b, bn_m, bn_v, W_ih, b_ih, W_hh, b_hh,
                     W1, b1, W2, b2, out);
}

// Round 6
// 805.477 us; speedup vs baseline: 8.0417x; 8.0417x over previous
//
#include <hip/hip_runtime.h>
#include <math.h>

#define T_STEPS 512
#define NF 4
#define HID 32
#define BN_EPS 1e-5f

typedef float    f32x2 __attribute__((ext_vector_type(2)));
typedef float    f32x4 __attribute__((ext_vector_type(4)));
typedef _Float16 f16x2 __attribute__((ext_vector_type(2)));
typedef _Float16 f16x8 __attribute__((ext_vector_type(8)));

// v_cvt_pkrtz_f16_f32 returns an __fp16-vector; bit_cast to our _Float16 vec
__device__ __forceinline__ f16x2 pk16(float x, float y) {
  return __builtin_bit_cast(f16x2, __builtin_amdgcn_cvt_pkrtz(x, y));
}

#if __has_builtin(__builtin_amdgcn_fdot2)
__device__ __forceinline__ float fdot2(f16x2 a, f16x2 b, float c) {
  return __builtin_amdgcn_fdot2(a, b, c, false);   // v_dot2_f32_f16: 2 MACs, fp32 acc
}
#else
__device__ __forceinline__ float fdot2(f16x2 a, f16x2 b, float c) {
  return fmaf((float)a.x, (float)b.x, fmaf((float)a.y, (float)b.y, c));
}
#endif

__device__ __forceinline__ float fsigmoid(float x) {
  return __builtin_amdgcn_rcpf(1.0f + __expf(-x));   // validated r1/r3: absmax 2e-3
}
__device__ __forceinline__ float ftanh(float x) {
  return fmaf(__builtin_amdgcn_rcpf(1.0f + __expf(-2.0f * x)), 2.0f, -1.0f);
}
template <int CTRL>
__device__ __forceinline__ float dpp_add(float v) {
  int s = __builtin_amdgcn_update_dpp(0, __builtin_bit_cast(int, v), CTRL, 0xf, 0xf, true);
  return v + __builtin_bit_cast(float, s);
}

// Wave = 2 batch rows. u = lane&31, half = (lane>>5)&1.
// Lower lane u owns gate-rows i_u,f_u; upper owns g_u,o_u — each computed for
// BOTH rows. f16 weights + v_dot2_f32_f16 halve register demand vs round 3/4
// (r3: 252 regs -> AGPR copy storm; r4: spill at the 128 cap -> 22.7 GB FETCH).
// Target: ~80 VGPRs, true 4 waves/SIMD, 4096 waves = exact one-round fit.
__global__ __launch_bounds__(256, 4) void hedge_kernel(
    const float* __restrict__ x,
    const float* __restrict__ bn_g, const float* __restrict__ bn_b,
    const float* __restrict__ bn_m, const float* __restrict__ bn_v,
    const float* __restrict__ W_ih, const float* __restrict__ b_ih,
    const float* __restrict__ W_hh, const float* __restrict__ b_hh,
    const float* __restrict__ W1,   const float* __restrict__ b1,
    const float* __restrict__ W2,   const float* __restrict__ b2,
    float* __restrict__ out)
{
  __shared__ __align__(16) _Float16 sh[4][2][HID];   // [wave][row][unit], 512 B

  const int tid  = threadIdx.x;
  const int u    = tid & 31;
  const int half = (tid >> 5) & 1;
  const int wv   = __builtin_amdgcn_readfirstlane(tid >> 6);
  const int rowA = (blockIdx.x * 4 + wv) * 2;

  // ---- fold BatchNorm (z*scale + shift) into W_ih' and bias
  float scale[5], shift[5];
  #pragma unroll
  for (int f = 0; f < 5; ++f) {
    float s = bn_g[f] * rsqrtf(bn_v[f] + BN_EPS);
    scale[f] = s;
    shift[f] = fmaf(-bn_m[f], s, bn_b[f]);
  }

  // gate rows owned by this lane: r0 = i_u / g_u, r1 = f_u / o_u
  const int r0 = half * 64 + u;
  const int r1 = r0 + 32;

  f16x2 wh0[16], wh1[16];           // W_hh rows r0,r1 as f16 pairs (16 VGPRs)
  f16x2 wx0a, wx0b, wx1a, wx1b;     // BN-scaled x-weights (4 VGPRs)
  float wd0, wd1, bias0, bias1;
  {
    float ws[5], acc = b_ih[r0] + b_hh[r0];
    #pragma unroll
    for (int f = 0; f < 5; ++f) {
      float w = W_ih[r0 * 5 + f];
      ws[f] = w * scale[f];
      acc = fmaf(w, shift[f], acc);
    }
    wx0a = pk16(ws[0], ws[1]);
    wx0b = pk16(ws[2], ws[3]);
    wd0 = ws[4]; bias0 = acc;
    #pragma unroll
    for (int p = 0; p < 16; ++p) {
      f32x2 w = *(const f32x2*)&W_hh[r0 * HID + 2 * p];
      wh0[p] = pk16(w.x, w.y);
    }
  }
  {
    float ws[5], acc = b_ih[r1] + b_hh[r1];
    #pragma unroll
    for (int f = 0; f < 5; ++f) {
      float w = W_ih[r1 * 5 + f];
      ws[f] = w * scale[f];
      acc = fmaf(w, shift[f], acc);
    }
    wx1a = pk16(ws[0], ws[1]);
    wx1b = pk16(ws[2], ws[3]);
    wd1 = ws[4]; bias1 = acc;
    #pragma unroll
    for (int p = 0; p < 16; ++p) {
      f32x2 w = *(const f32x2*)&W_hh[r1 * HID + 2 * p];
      wh1[p] = pk16(w.x, w.y);
    }
  }

  // MLP: lane = unit u, k-half [half*16, half*16+16), both rows (4 VGPRs)
  f16x2 w1h[8];
  #pragma unroll
  for (int p = 0; p < 8; ++p) {
    f32x2 w = *(const f32x2*)&W1[u * HID + half * 16 + 2 * p];
    w1h[p] = pk16(w.x, w.y);
  }
  const float b1u = b1[u];
  const float w2u = W2[u];
  const float b2s = b2[0];

  const float* xA = x + (size_t)rowA * (T_STEPS * NF);
  const float* xB = xA + T_STEPS * NF;
  float* orow = out + ((size_t)rowA + half) * T_STEPS;

  float c = 0.0f, h = 0.0f;

  // scalar gate accumulators [gate-row r0/r1][batch-row A/B]
  float acc00, acc01, acc10, acc11;
  {
    const f32x4 x0A = *(const f32x4*)xA;
    const f32x4 x0B = *(const f32x4*)xB;
    const f16x2 a01 = pk16(x0A.x, x0A.y);
    const f16x2 a23 = pk16(x0A.z, x0A.w);
    const f16x2 b01 = pk16(x0B.x, x0B.y);
    const f16x2 b23 = pk16(x0B.z, x0B.w);
    acc00 = fdot2(wx0b, a23, fdot2(wx0a, a01, bias0));
    acc01 = fdot2(wx0b, b23, fdot2(wx0a, b01, bias0));
    acc10 = fdot2(wx1b, a23, fdot2(wx1a, a01, bias1));
    acc11 = fdot2(wx1b, b23, fdot2(wx1a, b01, bias1));
  }

  const f16x8* shA8 = (const f16x8*)&sh[wv][0][0];
  const f16x8* shB8 = (const f16x8*)&sh[wv][1][0];
  const f16x8* mA8  = (const f16x8*)&sh[wv][0][half * 16];
  const f16x8* mB8  = (const f16x8*)&sh[wv][1][half * 16];

  #pragma unroll 1
  for (int t = 0; t < T_STEPS; ++t) {
    const int tn = (t + 1 < T_STEPS) ? t + 1 : t;
    const f32x4 xnA = *(const f32x4*)(xA + tn * NF);   // prefetch x_{t+1}
    const f32x4 xnB = *(const f32x4*)(xB + tn * NF);

    // ---- exchange: lower keeps row A (needs g,o from upper); upper keeps row B
    const float s0 = half ? acc00 : acc01;   // upper sends g^A, lower sends i^B
    const float s1 = half ? acc10 : acc11;   // upper sends o^A, lower sends f^B
    const float q0 = __shfl_xor(s0, 32);
    const float q1 = __shfl_xor(s1, 32);
    const float gi = half ? q0 : acc00;
    const float gf = half ? q1 : acc10;
    const float gg = half ? acc01 : q0;
    const float go = half ? acc11 : q1;

    const float I = fsigmoid(gi);
    const float F = fsigmoid(gf);
    const float G = ftanh(gg);
    const float O = fsigmoid(go);
    c = fmaf(F, c, I * G);
    h = O * ftanh(c);
    sh[wv][half][u] = (_Float16)h;   // same-wave producer/consumer: lgkmcnt orders

    // ---- acc(t+1) = bias + x_{t+1} terms (f16 dot2)
    {
      const f16x2 a01 = pk16(xnA.x, xnA.y);
      const f16x2 a23 = pk16(xnA.z, xnA.w);
      const f16x2 b01 = pk16(xnB.x, xnB.y);
      const f16x2 b23 = pk16(xnB.z, xnB.w);
      acc00 = fdot2(wx0b, a23, fdot2(wx0a, a01, bias0));
      acc01 = fdot2(wx0b, b23, fdot2(wx0a, b01, bias0));
      acc10 = fdot2(wx1b, a23, fdot2(wx1a, a01, bias1));
      acc11 = fdot2(wx1b, b23, fdot2(wx1a, b01, bias1));
    }

    // ---- h_t -> gates(t+1): 64 dot2 over broadcast f16x8 LDS reads
    #pragma unroll
    for (int i = 0; i < 4; ++i) {
      const f16x8 hA = shA8[i];
      const f16x8 hB = shB8[i];
      #pragma unroll
      for (int q = 0; q < 4; ++q) {
        const f16x2 ha = (f16x2){hA[2*q], hA[2*q+1]};
        const f16x2 hb = (f16x2){hB[2*q], hB[2*q+1]};
        acc00 = fdot2(wh0[4*i+q], ha, acc00);
        acc01 = fdot2(wh0[4*i+q], hb, acc01);
        acc10 = fdot2(wh1[4*i+q], ha, acc10);
        acc11 = fdot2(wh1[4*i+q], hb, acc11);
      }
    }

    // ---- decision MLP on h_t: unit u, my k-half, both rows (16 dot2)
    float pA = 0.0f, pB = 0.0f;
    #pragma unroll
    for (int i = 0; i < 2; ++i) {
      const f16x8 hA = mA8[i];
      const f16x8 hB = mB8[i];
      #pragma unroll
      for (int q = 0; q < 4; ++q) {
        const f16x2 ha = (f16x2){hA[2*q], hA[2*q+1]};
        const f16x2 hb = (f16x2){hB[2*q], hB[2*q+1]};
        pA = fdot2(w1h[4*i+q], ha, pA);
        pB = fdot2(w1h[4*i+q], hb, pB);
      }
    }
    const float ms = half ? pA : pB;         // send the partial the OTHER half completes
    const float mr = __shfl_xor(ms, 32);
    const float mval = (half ? pB : pA) + mr + b1u;
    float rv = fmaxf(mval, 0.f) * w2u;
    rv = dpp_add<0x111>(rv);   // row_shr:1
    rv = dpp_add<0x112>(rv);   // row_shr:2
    rv = dpp_add<0x114>(rv);   // row_shr:4
    rv = dpp_add<0x118>(rv);   // row_shr:8  -> lanes 15/31/47/63 = row-of-16 sums
    rv = dpp_add<0x142>(rv);   // row_bcast:15 -> lane31 = sumA, lane63 = sumB
    const float sv = fsigmoid(rv + b2s);
    const float dA = __builtin_bit_cast(float, __builtin_amdgcn_readlane(__builtin_bit_cast(int, sv), 31));
    const float dB = __builtin_bit_cast(float, __builtin_amdgcn_readlane(__builtin_bit_cast(int, sv), 63));

    // d_t term of gates(t+1) in fp32 (wd kept fp32)
    acc00 = fmaf(wd0, dA, acc00);
    acc01 = fmaf(wd0, dB, acc01);
    acc10 = fmaf(wd1, dA, acc10);
    acc11 = fmaf(wd1, dB, acc11);

    if (u == 0) orow[t] = half ? dB : dA;    // lane0 -> row A, lane32 -> row B
  }
}

extern "C" void kernel_launch(void* const* d_in, const int* in_sizes, int n_in,
                              void* d_out, int out_size, void* d_ws, size_t ws_size,
                              hipStream_t stream) {
  const float* x    = (const float*)d_in[0];
  const float* bn_g = (const float*)d_in[1];
  const float* bn_b = (const float*)d_in[2];
  const float* bn_m = (const float*)d_in[3];
  const float* bn_v = (const float*)d_in[4];
  const float* W_ih = (const float*)d_in[5];
  const float* b_ih = (const float*)d_in[6];
  const float* W_hh = (const float*)d_in[7];
  const float* b_hh = (const float*)d_in[8];
  const float* W1   = (const float*)d_in[9];
  const float* b1   = (const float*)d_in[10];
  const float* W2   = (const float*)d_in[11];
  const float* b2   = (const float*)d_in[12];
  float* out = (float*)d_out;

  const int B = in_sizes[0] / (T_STEPS * NF);   // 8192
  const int grid = B / 8;                       // 8 rows/block -> 1024 blocks

  hipLaunchKernelGGL(hedge_kernel, dim3(grid), dim3(256), 0, stream,
                     x, bn_g, bn_b, bn_m, bn_v, W_ih, b_ih, W_hh, b_hh,
                     W1, b1, W2, b2, out);
}